// Round 7
// baseline (117.484 us; speedup 1.0000x reference)
//
#include <hip/hip_runtime.h>
#include <math.h>

// out[b,i,j,f] = min_{di,dj,c} ( x[b,i+di,j+dj,c] - W[di,dj,c,f] )
// x: (16,128,128,16) f32, W: (3,3,16,32) f32, out: (16,126,126,32) f32
//
// R7: the R6 loop was ~70% latency-stalled (derived VALUBusy uses SIMD-16
// formula -> real VALU occ ~30%): per-iter 32B strided global reads miss
// L2 (FETCH=8.2MB) at ~900cy with only 1 iter of cover. Fix: the block's
// whole input tile is only 23 rows x 6 cols x 32B = 4.4KB -> stage it in
// LDS once (coalesced cooperative prologue), then the hot loop is
// ds_read_b128 broadcasts (conflict-free, prefetched 1 row ahead) + the
// irreducible packed-fp16 min-plus math (~15us chip-wide floor).

#define TI 21          // output rows per block; 126 = 21*6
#define TROWS (TI + 2) // input rows per tile
#define LROW 64        // LDS row stride in halves (48 used + pad)

typedef _Float16 h2 __attribute__((ext_vector_type(2)));

__device__ __forceinline__ h2 hmin2(h2 a, h2 b) {
    return __builtin_elementwise_min(a, b);  // v_pk_min_f16
}

__device__ __forceinline__ h2 pkrtz(float a, float b) {
    auto r = __builtin_amdgcn_cvt_pkrtz(a, b);  // v_cvt_pkrtz_f16_f32
    return *reinterpret_cast<h2*>(&r);
}

// min over 12 half2 of (hx[k] - w[k]) for one weight row di
__device__ __forceinline__ h2 rowmin(const h2* hx, const h2 w[3][4]) {
    h2 t[12];
#pragma unroll
    for (int dj = 0; dj < 3; ++dj)
#pragma unroll
        for (int q = 0; q < 4; ++q)
            t[dj * 4 + q] = hx[dj * 4 + q] - w[dj][q];  // v_pk_add_f16 neg
#pragma unroll
    for (int k = 0; k < 6; ++k) t[k] = hmin2(t[k], t[k + 6]);
    t[0] = hmin2(t[0], t[3]);
    t[1] = hmin2(t[1], t[4]);
    t[2] = hmin2(t[2], t[5]);
    return hmin2(hmin2(t[0], t[1]), t[2]);
}

// ---- pre-pass: x fp32 -> fp16, same layout ----
__global__ __launch_bounds__(256) void cvt_kernel(const float* __restrict__ x,
                                                  _Float16* __restrict__ xh) {
    int idx = (blockIdx.x * 256 + threadIdx.x) * 8;
    float4 a = *reinterpret_cast<const float4*>(x + idx);
    float4 b = *reinterpret_cast<const float4*>(x + idx + 4);
    h2 o[4] = { pkrtz(a.x, a.y), pkrtz(a.z, a.w), pkrtz(b.x, b.y), pkrtz(b.z, b.w) };
    *reinterpret_cast<float4*>(xh + idx) = *reinterpret_cast<float4*>(o);
}

// ---- main kernel: LDS-staged tile, packed-fp16 rolling window ----
__global__ __launch_bounds__(256) void erosion_h_kernel(
    const _Float16* __restrict__ xh, const float* __restrict__ Wt,
    float* __restrict__ out)
{
    // [ch:2][row:23][LROW=64 halves]; ch stride 23*64*2B = 2944B (bank-
    // aligned with ch0 -> 2-way same-bank in a wave, which is free).
    __shared__ _Float16 lds[2 * TROWS * LROW];

    const int tid = threadIdx.x;
    const int f  = tid & 31;
    const int ch = (tid >> 5) & 1;   // channel half: 0 -> c 0..7, 1 -> c 8..15
    const int jt = tid >> 6;         // column in block (wave-uniform)
    const int b  = blockIdx.z;
    const int i0 = blockIdx.y * TI;
    const int jb = blockIdx.x * 4;
    const int j  = jb + jt;          // 0..127
    const bool writer = (j < 126) && (ch == 0);

    // ---- cooperative tile load: 23 rows x 6 cols x 2 ch, 16B chunks ----
    // chunk t (t < 276): r = t/12, k = t%12 -> col = jb + k/2, ch2 = k&1.
    // Within a row the 12 chunks are 192B contiguous in global memory.
    {
        const _Float16* xg = xh + (size_t)b * (128 * 128 * 16);
#pragma unroll
        for (int pass = 0; pass < 2; ++pass) {
            int t = tid + pass * 256;
            if (t < TROWS * 12) {
                int r   = t / 12;
                int k   = t % 12;
                int cc  = k >> 1;          // 0..5 tile column
                int ch2 = k & 1;
                int col = min(jb + cc, 127);  // clamp edge block (j>=126 never stored)
                float4 v = *reinterpret_cast<const float4*>(
                    xg + ((size_t)(i0 + r) * 128 + col) * 16 + ch2 * 8);
                *reinterpret_cast<float4*>(
                    &lds[ch2 * (TROWS * LROW) + r * LROW + cc * 8]) = v;
            }
        }
    }

    // wh[di][dj][q] = { W[di,dj, ch*8+2q, f], W[di,dj, ch*8+2q+1, f] } as fp16
    h2 wh[3][3][4];
#pragma unroll
    for (int di = 0; di < 3; ++di)
#pragma unroll
        for (int dj = 0; dj < 3; ++dj)
#pragma unroll
            for (int q = 0; q < 4; ++q) {
                int p = di * 3 + dj;
                float a = Wt[(p * 16 + ch * 8 + 2 * q) * 32 + f];
                float c = Wt[(p * 16 + ch * 8 + 2 * q + 1) * 32 + f];
                wh[di][dj][q] = pkrtz(a, c);
            }

    __syncthreads();

    const _Float16* lb = &lds[ch * (TROWS * LROW) + jt * 8];  // row 0, col jt
    float* op = out + (((size_t)b * 126 + i0) * 126 + j) * 32 + f;

    const _Float16 HINF = (_Float16)__builtin_huge_valf();
    h2 accB = {HINF, HINF};  // partial min for output row r-1
    h2 accC = {HINF, HINF};  // partial min for output row r-2

    // pipeline regs: current row's 3 col-spans (16B each, contiguous in LDS)
    float4 pre[3];
#pragma unroll
    for (int dj = 0; dj < 3; ++dj)
        pre[dj] = *reinterpret_cast<const float4*>(lb + dj * 8);

    auto body = [&](int r, bool do_prefetch, bool do_store) {
        h2 hx[12];
#pragma unroll
        for (int dj = 0; dj < 3; ++dj) {
            const h2* p = reinterpret_cast<const h2*>(&pre[dj]);
            hx[dj * 4 + 0] = p[0];
            hx[dj * 4 + 1] = p[1];
            hx[dj * 4 + 2] = p[2];
            hx[dj * 4 + 3] = p[3];
        }
        if (do_prefetch) {
            const _Float16* ln = lb + (r + 1) * LROW;
#pragma unroll
            for (int dj = 0; dj < 3; ++dj)
                pre[dj] = *reinterpret_cast<const float4*>(ln + dj * 8);
        }

        h2 n0 = rowmin(hx, wh[0]);
        h2 n1 = rowmin(hx, wh[1]);
        h2 n2 = rowmin(hx, wh[2]);

        h2 fin2 = hmin2(accC, n2);  // output row r-2 complete
        accC = hmin2(accB, n1);
        accB = n0;

        if (do_store) {
            _Float16 vm = fin2[0] < fin2[1] ? fin2[0] : fin2[1];  // v_min_f16
            float v = (float)vm;
            v = fminf(v, __shfl_xor(v, 32));  // merge c-halves (lanes tid^32)
            if (writer)
                op[(size_t)(r - 2) * (126 * 32)] = v;
        }
    };

    body(0, true, false);
    body(1, true, false);
#pragma unroll 2
    for (int r = 2; r < TROWS - 1; ++r)
        body(r, true, true);
    body(TROWS - 1, false, true);
}

// ---- fallback (ws too small): in-kernel conversion, R3-style ----
__global__ __launch_bounds__(256) void erosion_kernel(
    const float* __restrict__ x, const float* __restrict__ Wt,
    float* __restrict__ out)
{
    const int tid = threadIdx.x;
    const int f  = tid & 31;
    const int ch = (tid >> 5) & 1;
    const int jt = tid >> 6;
    const int b  = blockIdx.z;
    const int i0 = blockIdx.y * TI;
    int j = blockIdx.x * 4 + jt;
    const bool jvalid = (j < 126);
    if (!jvalid) j = 125;

    h2 wh[3][3][4];
#pragma unroll
    for (int di = 0; di < 3; ++di)
#pragma unroll
        for (int dj = 0; dj < 3; ++dj)
#pragma unroll
            for (int q = 0; q < 4; ++q) {
                int p = di * 3 + dj;
                float a = Wt[(p * 16 + ch * 8 + 2 * q) * 32 + f];
                float c = Wt[(p * 16 + ch * 8 + 2 * q + 1) * 32 + f];
                wh[di][dj][q] = pkrtz(a, c);
            }

    const float* xb = x + ((size_t)b * 128 * 128 + (size_t)j) * 16 + ch * 8;
    float* op = out + (((size_t)b * 126 + i0) * 126 + j) * 32 + f;

    const _Float16 HINF = (_Float16)__builtin_huge_valf();
    h2 accB = {HINF, HINF};
    h2 accC = {HINF, HINF};

#pragma unroll 2
    for (int r = 0; r < TI + 2; ++r) {
        const float* xr = xb + (size_t)(i0 + r) * 2048;
        h2 hx[12];
#pragma unroll
        for (int dj = 0; dj < 3; ++dj) {
            float4 lo = *reinterpret_cast<const float4*>(xr + dj * 16);
            float4 hi = *reinterpret_cast<const float4*>(xr + dj * 16 + 4);
            hx[dj * 4 + 0] = pkrtz(lo.x, lo.y);
            hx[dj * 4 + 1] = pkrtz(lo.z, lo.w);
            hx[dj * 4 + 2] = pkrtz(hi.x, hi.y);
            hx[dj * 4 + 3] = pkrtz(hi.z, hi.w);
        }

        h2 n0 = rowmin(hx, wh[0]);
        h2 n1 = rowmin(hx, wh[1]);
        h2 n2 = rowmin(hx, wh[2]);

        h2 fin2 = hmin2(accC, n2);
        accC = hmin2(accB, n1);
        accB = n0;

        if (r >= 2) {
            _Float16 vm = fin2[0] < fin2[1] ? fin2[0] : fin2[1];
            float v = (float)vm;
            v = fminf(v, __shfl_xor(v, 32));
            if (jvalid && ch == 0)
                op[(size_t)(r - 2) * (126 * 32)] = v;
        }
    }
}

extern "C" void kernel_launch(void* const* d_in, const int* in_sizes, int n_in,
                              void* d_out, int out_size, void* d_ws, size_t ws_size,
                              hipStream_t stream) {
    const float* x  = (const float*)d_in[0];  // 16*128*128*16
    const float* Wt = (const float*)d_in[1];  // 3*3*16*32
    float* out = (float*)d_out;               // 16*126*126*32

    const size_t xelems = (size_t)16 * 128 * 128 * 16;  // 4,194,304
    dim3 grid(32, 6, 16);   // 3072 blocks
    dim3 block(256);

    if (ws_size >= xelems * sizeof(_Float16)) {
        _Float16* xh = (_Float16*)d_ws;
        cvt_kernel<<<dim3(xelems / (256 * 8)), block, 0, stream>>>(x, xh);
        erosion_h_kernel<<<grid, block, 0, stream>>>(xh, Wt, out);
    } else {
        erosion_kernel<<<grid, block, 0, stream>>>(x, Wt, out);
    }
}

// Round 8
// 113.644 us; speedup vs baseline: 1.0338x; 1.0338x over previous
//
#include <hip/hip_runtime.h>
#include <math.h>

// out[b,i,j,f] = min_{di,dj,c} ( x[b,i+di,j+dj,c] - W[di,dj,c,f] )
// x: (16,128,128,16) f32, W: (3,3,16,32) f32, out: (16,126,126,32) f32
//
// R8: single fused kernel. Block stages its fp32 tile -> converts to fp16
// in-flight (pkrtz) -> LDS, then runs the packed-fp16 rolling-window
// min-plus loop reading LDS directly under unroll-3. Removes the separate
// cvt dispatch and its 8.4MB+8.2MB HBM round trip (R3-R7 structure).
// TI=42 (126=42*3): 1536 blocks, halved prologue count vs TI=21.

#define TI 42          // output rows per block
#define TROWS (TI + 2) // input rows per tile (44)
#define LROW 64        // LDS row stride in halves (48 used + 16 pad)

typedef _Float16 h2 __attribute__((ext_vector_type(2)));

__device__ __forceinline__ h2 hmin2(h2 a, h2 b) {
    return __builtin_elementwise_min(a, b);  // v_pk_min_f16
}

__device__ __forceinline__ h2 pkrtz(float a, float b) {
    auto r = __builtin_amdgcn_cvt_pkrtz(a, b);  // v_cvt_pkrtz_f16_f32
    return *reinterpret_cast<h2*>(&r);
}

// min over 12 half2 of (hx[k] - w[k]) for one weight row di
__device__ __forceinline__ h2 rowmin(const h2* hx, const h2 w[3][4]) {
    h2 t[12];
#pragma unroll
    for (int dj = 0; dj < 3; ++dj)
#pragma unroll
        for (int q = 0; q < 4; ++q)
            t[dj * 4 + q] = hx[dj * 4 + q] - w[dj][q];  // v_pk_add_f16 neg
#pragma unroll
    for (int k = 0; k < 6; ++k) t[k] = hmin2(t[k], t[k + 6]);
    t[0] = hmin2(t[0], t[3]);
    t[1] = hmin2(t[1], t[4]);
    t[2] = hmin2(t[2], t[5]);
    return hmin2(hmin2(t[0], t[1]), t[2]);
}

__global__ __launch_bounds__(256) void erosion_kernel(
    const float* __restrict__ x, const float* __restrict__ Wt,
    float* __restrict__ out)
{
    // [ch:2][row:44][LROW=64 halves] = 11264 B
    __shared__ _Float16 lds[2 * TROWS * LROW];

    const int tid = threadIdx.x;
    const int f  = tid & 31;
    const int ch = (tid >> 5) & 1;   // channel half: 0 -> c 0..7, 1 -> c 8..15
    const int jt = tid >> 6;         // column in block (wave-uniform)
    const int b  = blockIdx.z;
    const int i0 = blockIdx.y * TI;
    const int jb = blockIdx.x * 4;
    const int j  = jb + jt;          // 0..127
    const bool writer = (j < 126) && (ch == 0);

    // ---- fused stage: fp32 tile -> fp16 LDS (44 rows x 6 cols x 2 ch) ----
    // group t (t < 528): r = t/12, k = t%12 -> col = jb + k/2, ch2 = k&1.
    // Each group: 8 floats (32B) -> 4 h2 (16B) -> one b128 LDS write.
    {
        const float* xg = x + (size_t)b * (128 * 128 * 16);
        for (int t = tid; t < TROWS * 12; t += 256) {
            int r   = t / 12;
            int k   = t % 12;
            int cc  = k >> 1;          // 0..5 tile column
            int ch2 = k & 1;
            int col = min(jb + cc, 127);  // clamp: only feeds never-stored outputs
            const float* src = xg + ((size_t)(i0 + r) * 128 + col) * 16 + ch2 * 8;
            float4 lo = *reinterpret_cast<const float4*>(src);
            float4 hi = *reinterpret_cast<const float4*>(src + 4);
            h2 o[4] = { pkrtz(lo.x, lo.y), pkrtz(lo.z, lo.w),
                        pkrtz(hi.x, hi.y), pkrtz(hi.z, hi.w) };
            *reinterpret_cast<float4*>(
                &lds[ch2 * (TROWS * LROW) + r * LROW + cc * 8]) =
                *reinterpret_cast<float4*>(o);
        }
    }

    // wh[di][dj][q] = { W[di,dj, ch*8+2q, f], W[di,dj, ch*8+2q+1, f] } as fp16
    h2 wh[3][3][4];
#pragma unroll
    for (int di = 0; di < 3; ++di)
#pragma unroll
        for (int dj = 0; dj < 3; ++dj)
#pragma unroll
            for (int q = 0; q < 4; ++q) {
                int p = di * 3 + dj;
                float a = Wt[(p * 16 + ch * 8 + 2 * q) * 32 + f];
                float c = Wt[(p * 16 + ch * 8 + 2 * q + 1) * 32 + f];
                wh[di][dj][q] = pkrtz(a, c);
            }

    __syncthreads();

    const _Float16* lb = &lds[ch * (TROWS * LROW) + jt * 8];  // row 0, col jt
    float* op = out + (((size_t)b * 126 + i0) * 126 + j) * 32 + f;

    const _Float16 HINF = (_Float16)__builtin_huge_valf();
    h2 accB = {HINF, HINF};  // partial min for output row r-1
    h2 accC = {HINF, HINF};  // partial min for output row r-2

    auto body = [&](int r, bool do_store) {
        // read current row's 3 col-spans straight from LDS (b128 each);
        // unroll-3 below lets the compiler pipeline these across sub-iters
        h2 hx[12];
#pragma unroll
        for (int dj = 0; dj < 3; ++dj) {
            float4 raw = *reinterpret_cast<const float4*>(lb + r * LROW + dj * 8);
            const h2* p = reinterpret_cast<const h2*>(&raw);
            hx[dj * 4 + 0] = p[0];
            hx[dj * 4 + 1] = p[1];
            hx[dj * 4 + 2] = p[2];
            hx[dj * 4 + 3] = p[3];
        }

        h2 n0 = rowmin(hx, wh[0]);
        h2 n1 = rowmin(hx, wh[1]);
        h2 n2 = rowmin(hx, wh[2]);

        h2 fin2 = hmin2(accC, n2);  // output row r-2 complete
        accC = hmin2(accB, n1);
        accB = n0;

        if (do_store) {
            _Float16 vm = fin2[0] < fin2[1] ? fin2[0] : fin2[1];  // v_min_f16
            float v = (float)vm;
            v = fminf(v, __shfl_xor(v, 32));  // merge c-halves (lanes tid^32)
            if (writer)
                op[(size_t)(r - 2) * (126 * 32)] = v;
        }
    };

    body(0, false);
    body(1, false);
#pragma unroll 3
    for (int r = 2; r < TROWS; ++r)   // 42 steady iters, 3-deep unroll
        body(r, true);
}

extern "C" void kernel_launch(void* const* d_in, const int* in_sizes, int n_in,
                              void* d_out, int out_size, void* d_ws, size_t ws_size,
                              hipStream_t stream) {
    const float* x  = (const float*)d_in[0];  // 16*128*128*16
    const float* Wt = (const float*)d_in[1];  // 3*3*16*32
    float* out = (float*)d_out;               // 16*126*126*32

    dim3 grid(32, 3, 16);   // 1536 blocks; 126 rows = 3 * TI
    dim3 block(256);
    erosion_kernel<<<grid, block, 0, stream>>>(x, Wt, out);
}